// Round 9
// baseline (132.045 us; speedup 1.0000x reference)
//
#include <hip/hip_runtime.h>
#include <math.h>

#define C_CLASSES 100000
#define FEAT      512
#define BATCH_N   32768
#define EPS_N     1e-12f

// ---------------- Kernel A: wave-per-row normalize-accumulate + ALIGNED float4 copy ----------------
// Copy target is d_out+1 (4B misaligned). We store the ALIGNED out-dword range
// [row*512, row*512+512) as float4s whose values are centers[g-1]:
//   out4[ln]    = { ln==0 ? centers[rbase-1]      : shfl_up(v0.w,1), v0.x, v0.y, v0.z }
//   out4[ln+64] = { ln==0 ? shfl(v0.w,63)         : shfl_up(v1.w,1), v1.x, v1.y, v1.z }
// Only 3 cross-lane ops per row (vs 15 scalar-shift), 4 VMEM instr (vs 16).
// All shuffles execute under full exec mask (R7 lesson: ds_bpermute from an
// inactive lane returns garbage). out[0] is the loss slot: row 0 / lane 0
// stores its 3 live components scalar. Final out dword written by final_loss.
__global__ void __launch_bounds__(256) centers_pass(
    const float* __restrict__ centers,
    float* __restrict__ out,           // d_out (dword-aligned base!)
    float* __restrict__ cpart,         // [gridDim.x * 512]
    float* __restrict__ rnorms)        // [C_CLASSES]
{
    const int t   = threadIdx.x;
    const int wid = t >> 6;
    const int ln  = t & 63;
    const int nb  = gridDim.x;

    float acc[8] = {0.f,0.f,0.f,0.f,0.f,0.f,0.f,0.f};

    for (int row = blockIdx.x * 4 + wid; row < C_CLASSES; row += nb * 4) {
        const size_t rbase = (size_t)row * FEAT;
        const float4* rp4 = reinterpret_cast<const float4*>(centers + rbase);

        const float4 v0 = rp4[ln];
        const float4 v1 = rp4[ln + 64];

        // previous row's last dword (uniform broadcast load, all lanes active)
        const float prev_row = (row > 0) ? centers[rbase - 1] : 0.f;

        float ss = v0.x*v0.x + v0.y*v0.y + v0.z*v0.z + v0.w*v0.w
                 + v1.x*v1.x + v1.y*v1.y + v1.z*v1.z + v1.w*v1.w;
        #pragma unroll
        for (int o = 32; o > 0; o >>= 1) ss += __shfl_xor(ss, o, 64);

        const float rn = 1.f / fmaxf(sqrtf(ss), EPS_N);
        if (ln == 0) rnorms[row] = rn;

        acc[0] += v0.x * rn; acc[1] += v0.y * rn; acc[2] += v0.z * rn; acc[3] += v0.w * rn;
        acc[4] += v1.x * rn; acc[5] += v1.y * rn; acc[6] += v1.z * rn; acc[7] += v1.w * rn;

        // cross-lane pieces for the dword shift (full exec mask!)
        const float w0up = __shfl_up(v0.w, 1, 64);   // lane ln-1's v0.w
        const float w1up = __shfl_up(v1.w, 1, 64);   // lane ln-1's v1.w
        const float w063 = __shfl(v0.w, 63, 64);     // lane 63's v0.w

        float4* op4 = reinterpret_cast<float4*>(out + rbase);
        const float4 s0 = make_float4((ln == 0) ? prev_row : w0up, v0.x, v0.y, v0.z);
        const float4 s1 = make_float4((ln == 0) ? w063     : w1up, v1.x, v1.y, v1.z);

        if (row == 0 && ln == 0) {
            // out[0] is the loss slot: store only dwords 1..3
            out[1] = s0.y; out[2] = s0.z; out[3] = s0.w;
        } else {
            op4[ln] = s0;
        }
        op4[ln + 64] = s1;
    }

    __shared__ float accsh[4][FEAT];
    #pragma unroll
    for (int k = 0; k < 8; ++k) accsh[wid][(k & 3) * 4 + (k >> 2) * 256 + 0] = 0.f; // (placeholder overwritten below)
    // store accumulators in feature order: acc[k] holds component k of the row layout
    accsh[wid][4*ln + 0] = acc[0]; accsh[wid][4*ln + 1] = acc[1];
    accsh[wid][4*ln + 2] = acc[2]; accsh[wid][4*ln + 3] = acc[3];
    accsh[wid][256 + 4*ln + 0] = acc[4]; accsh[wid][256 + 4*ln + 1] = acc[5];
    accsh[wid][256 + 4*ln + 2] = acc[6]; accsh[wid][256 + 4*ln + 3] = acc[7];
    __syncthreads();

    #pragma unroll
    for (int j = t; j < FEAT; j += 256)
        cpart[(size_t)blockIdx.x * FEAT + j] =
            accsh[0][j] + accsh[1][j] + accsh[2][j] + accsh[3][j];
}

// ---------------- Kernel B1: parallel partial reduce over cpart blocks ----------------
__global__ void __launch_bounds__(512) reduce_mean_s1(
    const float* __restrict__ cpart, int nblk,
    float* __restrict__ partial2)
{
    const int j = threadIdx.x;             // feature
    float s = 0.f;
    for (int b = blockIdx.x; b < nblk; b += gridDim.x)
        s += cpart[(size_t)b * FEAT + j];
    partial2[(size_t)blockIdx.x * FEAT + j] = s;
}

// ---------------- Kernel B2: finish -> mean[512] ----------------
__global__ void __launch_bounds__(512) reduce_mean_s2(
    const float* __restrict__ partial2, int np,
    float* __restrict__ mean)
{
    const int j = threadIdx.x;
    float s = 0.f;
    for (int p = 0; p < np; ++p)
        s += partial2[(size_t)p * FEAT + j];
    mean[j] = s / (float)C_CLASSES;
}

// ---------------- Kernel C: per-x-row loss terms (one wave per row) ----------------
__global__ void __launch_bounds__(256) row_loss(
    const float* __restrict__ x,
    const int*   __restrict__ labels,
    const float* __restrict__ centers,
    const float* __restrict__ mean,
    const float* __restrict__ rnorms,
    float* __restrict__ lpart)          // [gridDim.x * 2]
{
    const int wid = threadIdx.x >> 6;
    const int ln  = threadIdx.x & 63;
    const int row = blockIdx.x * 4 + wid;

    const float4* __restrict__ xr = reinterpret_cast<const float4*>(x + (size_t)row * FEAT);
    const float4* __restrict__ mr = reinterpret_cast<const float4*>(mean);
    const int lab = labels[row];
    const float4* __restrict__ cr = reinterpret_cast<const float4*>(centers + (size_t)lab * FEAT);
    const float rnc = rnorms[lab];

    const float4 xv0 = xr[ln], xv1 = xr[ln + 64];
    const float4 mv0 = mr[ln], mv1 = mr[ln + 64];
    const float4 cv0 = cr[ln], cv1 = cr[ln + 64];

    float ssx = xv0.x*xv0.x + xv0.y*xv0.y + xv0.z*xv0.z + xv0.w*xv0.w
              + xv1.x*xv1.x + xv1.y*xv1.y + xv1.z*xv1.z + xv1.w*xv1.w;
    float dxm = xv0.x*mv0.x + xv0.y*mv0.y + xv0.z*mv0.z + xv0.w*mv0.w
              + xv1.x*mv1.x + xv1.y*mv1.y + xv1.z*mv1.z + xv1.w*mv1.w;
    float dxc = xv0.x*cv0.x + xv0.y*cv0.y + xv0.z*cv0.z + xv0.w*cv0.w
              + xv1.x*cv1.x + xv1.y*cv1.y + xv1.z*cv1.z + xv1.w*cv1.w;

    #pragma unroll
    for (int o = 32; o > 0; o >>= 1) {
        ssx += __shfl_xor(ssx, o, 64);
        dxm += __shfl_xor(dxm, o, 64);
        dxc += __shfl_xor(dxc, o, 64);
    }

    __shared__ float t1s[4], t2s[4];
    if (ln == 0) {
        const float rnx = 1.f / fmaxf(sqrtf(ssx), EPS_N);
        const float s_all = dxm * rnx;
        const float s_lab = dxc * rnx * rnc;
        const float e_all = expf(s_all);
        const float kC    = (float)((double)(C_CLASSES + 1) / (double)C_CLASSES);
        const float t1 = (e_all - expf(s_lab * kC));                        // / ALPHA1 (=1)
        const float t2 = -fabsf((e_all - expf(s_lab) + 0.2f) * (1.f / 50.f));
        t1s[wid] = t1;
        t2s[wid] = t2;
    }
    __syncthreads();
    if (threadIdx.x == 0) {
        lpart[(size_t)blockIdx.x * 2]     = t1s[0] + t1s[1] + t1s[2] + t1s[3];
        lpart[(size_t)blockIdx.x * 2 + 1] = t2s[0] + t2s[1] + t2s[2] + t2s[3];
    }
}

// ---------------- Kernel D: final reduction + blend + copy tail ----------------
__global__ void final_loss(const float* __restrict__ lpart, int n,
                           const int* __restrict__ epoch,
                           const float* __restrict__ centers,
                           float* __restrict__ out)
{
    __shared__ double sh1[256];
    __shared__ double sh2[256];
    double s1 = 0.0, s2 = 0.0;
    for (int i = threadIdx.x; i < n; i += blockDim.x) {
        s1 += (double)lpart[(size_t)i * 2];
        s2 += (double)lpart[(size_t)i * 2 + 1];
    }
    sh1[threadIdx.x] = s1;
    sh2[threadIdx.x] = s2;
    __syncthreads();
    for (int s = 128; s > 0; s >>= 1) {
        if (threadIdx.x < s) {
            sh1[threadIdx.x] += sh1[threadIdx.x + s];
            sh2[threadIdx.x] += sh2[threadIdx.x + s];
        }
        __syncthreads();
    }
    if (threadIdx.x == 0) {
        const float v  = fminf((float)(*epoch) * (1.f / 14.f), 1.f);
        const float l1 = (float)(sh1[0] / (double)BATCH_N);
        const float l2 = (float)(sh2[0] / (double)BATCH_N);
        out[0] = (1.f - v) * l1 + v * l2;
    }
    if (threadIdx.x == 1) {
        // last copy dword not covered by the shifted store pattern
        const size_t g = (size_t)C_CLASSES * FEAT;
        out[g] = centers[g - 1];
    }
}

extern "C" void kernel_launch(void* const* d_in, const int* in_sizes, int n_in,
                              void* d_out, int out_size, void* d_ws, size_t ws_size,
                              hipStream_t stream)
{
    const float* x       = (const float*)d_in[0];
    const int*   labels  = (const int*)d_in[1];
    // d_in[2] = ori_labels (unused by reference)
    const int*   epoch   = (const int*)d_in[3];
    const float* centers = (const float*)d_in[4];
    float* out = (float*)d_out;

    float* ws       = (float*)d_ws;
    float* mean     = ws;                       // 512
    float* partial2 = ws + 512;                 // 32*512
    float* lpart    = ws + 512 + 16384;         // (BATCH_N/4)*2
    float* rnorms   = ws + 512 + 16384 + 16384; // C_CLASSES (100000, pad to 100352)
    float* cpart    = rnorms + 100352;          // nblkA * 512

    const size_t fixed_bytes = (size_t)(512 + 16384 + 16384 + 100352) * sizeof(float);
    int nblkA = 2048;
    if (ws_size < fixed_bytes + (size_t)nblkA * FEAT * sizeof(float)) {
        size_t avail = (ws_size > fixed_bytes) ? (ws_size - fixed_bytes) : 0;
        nblkA = (int)(avail / (FEAT * sizeof(float)));
        if (nblkA < 1) nblkA = 1;
    }

    centers_pass<<<nblkA, 256, 0, stream>>>(centers, out, cpart, rnorms);
    reduce_mean_s1<<<32, 512, 0, stream>>>(cpart, nblkA, partial2);
    reduce_mean_s2<<<1, 512, 0, stream>>>(partial2, 32, mean);
    row_loss<<<BATCH_N / 4, 256, 0, stream>>>(x, labels, centers, mean, rnorms, lpart);
    final_loss<<<1, 256, 0, stream>>>(lpart, BATCH_N / 4, epoch, centers, out);
}

// Round 10
// 122.312 us; speedup vs baseline: 1.0796x; 1.0796x over previous
//
#include <hip/hip_runtime.h>
#include <math.h>

#define C_CLASSES 100000
#define FEAT      512
#define BATCH_N   32768
#define EPS_N     1e-12f
#define NBLKA     2048
#define MSLOTS    32
#define LSLOTS    64
#define FIX_SCALE 4294967296.0   // 2^32

// ---------------- Kernel A: wave-per-row normalize-accumulate + ALIGNED copy ----------------
// Stores issue BEFORE the sum-of-squares reduce (they depend only on the loads
// + 3 shift shuffles), so the write stream is not serialized behind the
// 6-bpermute reduction chain. Block partial means go to int64 fixed-point
// atomic slots (deterministic: integer adds are order-independent).
__global__ void __launch_bounds__(256) centers_pass(
    const float* __restrict__ centers,
    float* __restrict__ out,                       // d_out (aligned base)
    unsigned long long* __restrict__ mslots,       // [MSLOTS*FEAT] fixed-point
    float* __restrict__ rnorms)                    // [C_CLASSES]
{
    const int t   = threadIdx.x;
    const int wid = t >> 6;
    const int ln  = t & 63;
    const int nb  = gridDim.x;

    float acc[8] = {0.f,0.f,0.f,0.f,0.f,0.f,0.f,0.f};

    for (int row = blockIdx.x * 4 + wid; row < C_CLASSES; row += nb * 4) {
        const size_t rbase = (size_t)row * FEAT;
        const float4* rp4 = reinterpret_cast<const float4*>(centers + rbase);

        const float4 v0 = rp4[ln];
        const float4 v1 = rp4[ln + 64];
        const float prev_row = (row > 0) ? centers[rbase - 1] : 0.f;

        // ---- shifted aligned copy FIRST (depends only on loads) ----
        const float w0up = __shfl_up(v0.w, 1, 64);      // full exec mask
        const float w1up = __shfl_up(v1.w, 1, 64);
        const float w063 = __shfl(v0.w, 63, 64);

        float4* op4 = reinterpret_cast<float4*>(out + rbase);
        const float4 s0 = make_float4((ln == 0) ? prev_row : w0up, v0.x, v0.y, v0.z);
        const float4 s1 = make_float4((ln == 0) ? w063     : w1up, v1.x, v1.y, v1.z);
        if (row == 0 && ln == 0) {
            out[1] = s0.y; out[2] = s0.z; out[3] = s0.w;   // out[0] = loss slot
        } else {
            op4[ln] = s0;
        }
        op4[ln + 64] = s1;

        // ---- then the reduction ----
        float ss = v0.x*v0.x + v0.y*v0.y + v0.z*v0.z + v0.w*v0.w
                 + v1.x*v1.x + v1.y*v1.y + v1.z*v1.z + v1.w*v1.w;
        #pragma unroll
        for (int o = 32; o > 0; o >>= 1) ss += __shfl_xor(ss, o, 64);

        const float rn = 1.f / fmaxf(sqrtf(ss), EPS_N);
        if (ln == 0) rnorms[row] = rn;

        acc[0] += v0.x * rn; acc[1] += v0.y * rn; acc[2] += v0.z * rn; acc[3] += v0.w * rn;
        acc[4] += v1.x * rn; acc[5] += v1.y * rn; acc[6] += v1.z * rn; acc[7] += v1.w * rn;
    }

    __shared__ float accsh[4][FEAT];
    accsh[wid][4*ln + 0] = acc[0]; accsh[wid][4*ln + 1] = acc[1];
    accsh[wid][4*ln + 2] = acc[2]; accsh[wid][4*ln + 3] = acc[3];
    accsh[wid][256 + 4*ln + 0] = acc[4]; accsh[wid][256 + 4*ln + 1] = acc[5];
    accsh[wid][256 + 4*ln + 2] = acc[6]; accsh[wid][256 + 4*ln + 3] = acc[7];
    __syncthreads();

    const int slot = (blockIdx.x & (MSLOTS - 1)) * FEAT;
    for (int j = t; j < FEAT; j += 256) {
        const float v = accsh[0][j] + accsh[1][j] + accsh[2][j] + accsh[3][j];
        const long long q = llrint((double)v * FIX_SCALE);
        atomicAdd(&mslots[slot + j], (unsigned long long)q);
    }
}

// ---------------- Kernel B: mslots -> mean[512] ----------------
__global__ void __launch_bounds__(512) mean_fin(
    const unsigned long long* __restrict__ mslots,
    float* __restrict__ mean)
{
    const int j = threadIdx.x;
    long long s = 0;
    #pragma unroll
    for (int p = 0; p < MSLOTS; ++p)
        s += (long long)mslots[(size_t)p * FEAT + j];
    mean[j] = (float)((double)s * (1.0 / FIX_SCALE) / (double)C_CLASSES);
}

// ---------------- Kernel C: per-x-row loss terms (one wave per row) ----------------
__global__ void __launch_bounds__(256) row_loss(
    const float* __restrict__ x,
    const int*   __restrict__ labels,
    const float* __restrict__ centers,
    const float* __restrict__ mean,
    const float* __restrict__ rnorms,
    unsigned long long* __restrict__ lslots)       // [LSLOTS*2] fixed-point
{
    const int wid = threadIdx.x >> 6;
    const int ln  = threadIdx.x & 63;
    const int row = blockIdx.x * 4 + wid;

    const float4* __restrict__ xr = reinterpret_cast<const float4*>(x + (size_t)row * FEAT);
    const float4* __restrict__ mr = reinterpret_cast<const float4*>(mean);
    const int lab = labels[row];
    const float4* __restrict__ cr = reinterpret_cast<const float4*>(centers + (size_t)lab * FEAT);
    const float rnc = rnorms[lab];

    const float4 xv0 = xr[ln], xv1 = xr[ln + 64];
    const float4 mv0 = mr[ln], mv1 = mr[ln + 64];
    const float4 cv0 = cr[ln], cv1 = cr[ln + 64];

    float ssx = xv0.x*xv0.x + xv0.y*xv0.y + xv0.z*xv0.z + xv0.w*xv0.w
              + xv1.x*xv1.x + xv1.y*xv1.y + xv1.z*xv1.z + xv1.w*xv1.w;
    float dxm = xv0.x*mv0.x + xv0.y*mv0.y + xv0.z*mv0.z + xv0.w*mv0.w
              + xv1.x*mv1.x + xv1.y*mv1.y + xv1.z*mv1.z + xv1.w*mv1.w;
    float dxc = xv0.x*cv0.x + xv0.y*cv0.y + xv0.z*cv0.z + xv0.w*cv0.w
              + xv1.x*cv1.x + xv1.y*cv1.y + xv1.z*cv1.z + xv1.w*cv1.w;

    #pragma unroll
    for (int o = 32; o > 0; o >>= 1) {
        ssx += __shfl_xor(ssx, o, 64);
        dxm += __shfl_xor(dxm, o, 64);
        dxc += __shfl_xor(dxc, o, 64);
    }

    __shared__ float t1s[4], t2s[4];
    if (ln == 0) {
        const float rnx = 1.f / fmaxf(sqrtf(ssx), EPS_N);
        const float s_all = dxm * rnx;
        const float s_lab = dxc * rnx * rnc;
        const float e_all = expf(s_all);
        const float kC    = (float)((double)(C_CLASSES + 1) / (double)C_CLASSES);
        t1s[wid] = (e_all - expf(s_lab * kC));                        // / ALPHA1 (=1)
        t2s[wid] = -fabsf((e_all - expf(s_lab) + 0.2f) * (1.f / 50.f));
    }
    __syncthreads();
    if (threadIdx.x == 0) {
        const double b1 = (double)t1s[0] + t1s[1] + t1s[2] + t1s[3];
        const double b2 = (double)t2s[0] + t2s[1] + t2s[2] + t2s[3];
        const int slot = (blockIdx.x & (LSLOTS - 1)) * 2;
        atomicAdd(&lslots[slot + 0], (unsigned long long)llrint(b1 * FIX_SCALE));
        atomicAdd(&lslots[slot + 1], (unsigned long long)llrint(b2 * FIX_SCALE));
    }
}

// ---------------- Kernel D: finalize loss + copy tail dword ----------------
__global__ void loss_fin(const unsigned long long* __restrict__ lslots,
                         const int* __restrict__ epoch,
                         const float* __restrict__ centers,
                         float* __restrict__ out)
{
    if (threadIdx.x == 0) {
        long long q1 = 0, q2 = 0;
        for (int p = 0; p < LSLOTS; ++p) {
            q1 += (long long)lslots[(size_t)p * 2 + 0];
            q2 += (long long)lslots[(size_t)p * 2 + 1];
        }
        const float v  = fminf((float)(*epoch) * (1.f / 14.f), 1.f);
        const float l1 = (float)((double)q1 * (1.0 / FIX_SCALE) / (double)BATCH_N);
        const float l2 = (float)((double)q2 * (1.0 / FIX_SCALE) / (double)BATCH_N);
        out[0] = (1.f - v) * l1 + v * l2;
    }
    if (threadIdx.x == 1) {
        const size_t g = (size_t)C_CLASSES * FEAT;   // last copy dword
        out[g] = centers[g - 1];
    }
}

extern "C" void kernel_launch(void* const* d_in, const int* in_sizes, int n_in,
                              void* d_out, int out_size, void* d_ws, size_t ws_size,
                              hipStream_t stream)
{
    const float* x       = (const float*)d_in[0];
    const int*   labels  = (const int*)d_in[1];
    // d_in[2] = ori_labels (unused by reference)
    const int*   epoch   = (const int*)d_in[3];
    const float* centers = (const float*)d_in[4];
    float* out = (float*)d_out;

    float* ws = (float*)d_ws;
    float* mean = ws;                                              // 512 f
    unsigned long long* mslots = (unsigned long long*)(ws + 512);  // 32*512 ll (8B-aligned)
    unsigned long long* lslots = mslots + (size_t)MSLOTS * FEAT;   // 64*2 ll
    float* rnorms = ws + 512 + 2 * (MSLOTS * FEAT + LSLOTS * 2);   // C_CLASSES floats

    // zero the atomic slots (capture-safe async memset)
    hipMemsetAsync(mslots, 0,
                   (size_t)(MSLOTS * FEAT + LSLOTS * 2) * sizeof(unsigned long long),
                   stream);

    centers_pass<<<NBLKA, 256, 0, stream>>>(centers, out, mslots, rnorms);
    mean_fin<<<1, 512, 0, stream>>>(mslots, mean);
    row_loss<<<BATCH_N / 4, 256, 0, stream>>>(x, labels, centers, mean, rnorms, lslots);
    loss_fin<<<1, 64, 0, stream>>>(lslots, epoch, centers, out);
}